// Round 1
// baseline (414.975 us; speedup 1.0000x reference)
//
#include <hip/hip_runtime.h>

// ---------------------------------------------------------------- constants
#define TTOK 32768
#define DM   256
#define NF   1024
#define KMAX 32

typedef __attribute__((ext_vector_type(8))) unsigned short ushort8;
typedef __attribute__((ext_vector_type(8))) __bf16 bf16x8;
typedef __attribute__((ext_vector_type(4))) float floatx4;

// workspace offsets (all 256B aligned)
constexpr size_t O_SLOT = 0;                                   // 1 uint (max|Wt|)
constexpr size_t O_S    = 256;                                 // 1024 f32 sigmoid(alpha)
constexpr size_t O_WCT  = O_S    + 4096;                       // Wc^T  [1024][256] bf16
constexpr size_t O_WGT  = O_WCT  + (size_t)NF*DM*2;            // Wg^T  [1024][256] bf16
constexpr size_t O_WDT  = O_WGT  + (size_t)NF*DM*2;            // Wd^T  [256][1024] bf16
constexpr size_t O_WTT  = O_WDT  + (size_t)DM*NF*2;            // Wt^T  [256][1024] f32
constexpr size_t O_XBF  = O_WTT  + (size_t)DM*NF*4;            // x bf16 [T][256]
constexpr size_t O_CNT  = O_XBF  + (size_t)TTOK*DM*2;          // counts [T]
constexpr size_t O_CIDX = O_CNT  + (size_t)TTOK*4;             // cand idx [T][KMAX]
constexpr size_t O_CVAL = O_CIDX + (size_t)TTOK*KMAX*4;        // cand val [T][KMAX]
constexpr size_t O_TROP = O_CVAL + (size_t)TTOK*KMAX*4;        // trop bf16 [T][1024]
constexpr size_t O_FUSD = O_TROP + (size_t)TTOK*NF*2;          // fused bf16 [T][1024]

__device__ __forceinline__ float bf2f(unsigned short u) {
    union { unsigned int i; float f; } c; c.i = ((unsigned int)u) << 16; return c.f;
}
__device__ __forceinline__ unsigned short f2bf(float v) {
    union { float f; unsigned int i; } c; c.f = v;
    unsigned int b = c.i;
    return (unsigned short)((b + 0x7FFFu + ((b >> 16) & 1u)) >> 16);
}
__device__ __forceinline__ float sigm(float z) { return 1.0f / (1.0f + __expf(-z)); }
// tanh-gelu: max |diff| vs exact erf-gelu ~3e-3, far under 0.266 tolerance
__device__ __forceinline__ float gelu_f(float x) {
    return x * sigm(1.59576912f * (x + 0.044715f * x * x * x));
}

// ------------------------------------------------- kernel 1: pack weights
// grid 1024 x 256 : e in [0, 262144)
__global__ void pack_kernel(const float* __restrict__ Wt, const float* __restrict__ alpha,
                            const float* __restrict__ Wc, const float* __restrict__ Wg,
                            const float* __restrict__ Wd,
                            unsigned short* __restrict__ Wct, unsigned short* __restrict__ Wgt,
                            unsigned short* __restrict__ WdT, float* __restrict__ WtT,
                            float* __restrict__ s, unsigned int* __restrict__ slot) {
    int e = blockIdx.x * 256 + threadIdx.x;
    if (e == 0) *slot = 0u;
    { int f = e >> 8, k = e & 255;           // Wc/Wg are [256][1024]
      Wct[e] = f2bf(Wc[k * NF + f]);
      Wgt[e] = f2bf(Wg[k * NF + f]); }
    { int n = e >> 10, k = e & 1023;         // Wd is [1024][256]
      WdT[e] = f2bf(Wd[k * DM + n]); }
    { int d = e >> 10, f = e & 1023;         // Wt is [1024][256]
      WtT[e] = Wt[f * DM + d]; }
    if (e < NF) s[e] = sigm(alpha[e]);
}

// ------------------------------------------------- kernel 2: max|Wt| reduce
__global__ void minmax_kernel(const float* __restrict__ Wt, unsigned int* __restrict__ slot) {
    int g = blockIdx.x * 256 + threadIdx.x;
    float lm = 0.0f;
    for (int i = g; i < NF * DM; i += 128 * 256) lm = fmaxf(lm, fabsf(Wt[i]));
    #pragma unroll
    for (int o = 32; o > 0; o >>= 1) lm = fmaxf(lm, __shfl_xor(lm, o));
    if ((threadIdx.x & 63) == 0) atomicMax(slot, __float_as_uint(lm)); // |w|>=0: uint order ok
}

// ------------------------------------------------- kernel 3: candidates + x->bf16
// one block (256 thr) per token
__global__ void cand_kernel(const float* __restrict__ x, const unsigned int* __restrict__ slot,
                            unsigned short* __restrict__ xbf, int* __restrict__ counts,
                            int* __restrict__ cidx, float* __restrict__ cval) {
    int i = blockIdx.x, t = threadIdx.x;
    float v = x[i * DM + t];
    xbf[i * DM + t] = f2bf(v);
    float m = v;
    #pragma unroll
    for (int o = 32; o > 0; o >>= 1) m = fmaxf(m, __shfl_xor(m, o));
    __shared__ float wm[4];
    __shared__ int cnt;
    __shared__ int sidx[KMAX];
    __shared__ float sval[KMAX];
    if ((t & 63) == 0) wm[t >> 6] = m;
    if (t == 0) cnt = 0;
    __syncthreads();
    float xmax = fmaxf(fmaxf(wm[0], wm[1]), fmaxf(wm[2], wm[3]));
    float delta = 2.0f * __uint_as_float(*slot);   // >= Wmax - Wmin : exact exclusion bound
    float thr = xmax - delta;
    if (v >= thr) {
        int p = atomicAdd(&cnt, 1);
        if (p < KMAX) { sidx[p] = t; sval[p] = v; }
    }
    __syncthreads();
    int c = cnt;
    if (t == 0) counts[i] = c;
    if (t < (c < KMAX ? c : KMAX)) {
        cidx[i * KMAX + t] = sidx[t];
        cval[i * KMAX + t] = sval[t];
    }
}

// ------------------------------------------------- kernel 4: tropical part
// block 256 thr handles 32 tokens x 1024 features; grid = TTOK/32
__global__ void trop_kernel(const float* __restrict__ x, const float* __restrict__ bt,
                            const float* __restrict__ slx, const float* __restrict__ ofx,
                            const float* __restrict__ slc, const float* __restrict__ ofc,
                            const float* __restrict__ s, const float* __restrict__ WtT,
                            const int* __restrict__ counts, const int* __restrict__ cidx,
                            const float* __restrict__ cval, unsigned short* __restrict__ trop) {
    __shared__ int sK[32];
    __shared__ int sIdx[32][KMAX];
    __shared__ float sVal[32][KMAX];
    int t = threadIdx.x, tok0 = blockIdx.x * 32;
    if (t < 32) sK[t] = counts[tok0 + t];
    for (int e = t; e < 32 * KMAX; e += 256) {
        int tk = e / KMAX, k = e % KMAX;
        sIdx[tk][k] = cidx[(tok0 + tk) * KMAX + k];
        sVal[tk][k] = cval[(tok0 + tk) * KMAX + k];
    }
    __syncthreads();
    for (int j = 0; j < 4; j++) {
        int f = j * 256 + t;
        float4 a0 = *(const float4*)(slx + f * 8), a1 = *(const float4*)(slx + f * 8 + 4);
        float4 b0 = *(const float4*)(ofx + f * 8), b1 = *(const float4*)(ofx + f * 8 + 4);
        float4 c0 = *(const float4*)(slc + f * 8), c1 = *(const float4*)(slc + f * 8 + 4);
        float4 d0 = *(const float4*)(ofc + f * 8), d1 = *(const float4*)(ofc + f * 8 + 4);
        float btf = bt[f], sf = s[f];
        for (int tk = 0; tk < 32; tk++) {
            int K = sK[tk];
            float tm = -1e30f;
            if (K <= KMAX) {
                for (int k = 0; k < K; k++)
                    tm = fmaxf(tm, sVal[tk][k] + WtT[sIdx[tk][k] * NF + f]);
            } else { // exact fallback (never expected, correctness guard)
                const float* xr = x + (tok0 + tk) * DM;
                for (int d = 0; d < DM; d++) tm = fmaxf(tm, xr[d] + WtT[d * NF + f]);
            }
            float z = tm + btf;
            float cvx = fmaf(z, a0.x, b0.x);
            cvx = fmaxf(cvx, fmaf(z, a0.y, b0.y));
            cvx = fmaxf(cvx, fmaf(z, a0.z, b0.z));
            cvx = fmaxf(cvx, fmaf(z, a0.w, b0.w));
            cvx = fmaxf(cvx, fmaf(z, a1.x, b1.x));
            cvx = fmaxf(cvx, fmaf(z, a1.y, b1.y));
            cvx = fmaxf(cvx, fmaf(z, a1.z, b1.z));
            cvx = fmaxf(cvx, fmaf(z, a1.w, b1.w));
            float ccv = fmaf(z, c0.x, d0.x);
            ccv = fminf(ccv, fmaf(z, c0.y, d0.y));
            ccv = fminf(ccv, fmaf(z, c0.z, d0.z));
            ccv = fminf(ccv, fmaf(z, c0.w, d0.w));
            ccv = fminf(ccv, fmaf(z, c1.x, d1.x));
            ccv = fminf(ccv, fmaf(z, c1.y, d1.y));
            ccv = fminf(ccv, fmaf(z, c1.z, d1.z));
            ccv = fminf(ccv, fmaf(z, c1.w, d1.w));
            float tv = sf * cvx + (1.0f - sf) * ccv;
            trop[(tok0 + tk) * NF + f] = f2bf(tv);
        }
    }
}

// ------------------------------------------------- kernel 5: GEMM1 (x@Wc, x@Wg fused)
// 128(M) x 128(F) tile, BK=32, 4 waves in 2x2, each wave 64x64 (4x4 mfma tiles) for BOTH c & g
#define LDSS 40  // 32 + 8 pad (ushorts) -> 80B row stride, 2-way bank alias (free)
__global__ __launch_bounds__(256) void gemm1_kernel(
    const unsigned short* __restrict__ A,   // xbf [T][256]
    const unsigned short* __restrict__ Bct, // [1024][256]
    const unsigned short* __restrict__ Bgt, // [1024][256]
    const float* __restrict__ bc, const float* __restrict__ bg,
    const unsigned short* __restrict__ trop, unsigned short* __restrict__ fused) {
    __shared__ __align__(16) unsigned short As[128 * LDSS];
    __shared__ __align__(16) unsigned short Bcs[128 * LDSS];
    __shared__ __align__(16) unsigned short Bgs[128 * LDSS];
    const int t = threadIdx.x;
    const int bm = blockIdx.x, bf = blockIdx.y;
    const int wave = t >> 6, lane = t & 63;
    const int wm = wave & 1, wn = wave >> 1;
    const int lr = lane & 15, quad = lane >> 4;

    floatx4 accc[4][4], accg[4][4];
    #pragma unroll
    for (int i = 0; i < 4; i++)
        #pragma unroll
        for (int j = 0; j < 4; j++) { accc[i][j] = (floatx4)0.0f; accg[i][j] = (floatx4)0.0f; }

    for (int k0 = 0; k0 < DM; k0 += 32) {
        __syncthreads();
        #pragma unroll
        for (int i = 0; i < 2; i++) {
            int lin = i * 256 + t, srow = lin >> 2, scol = (lin & 3) << 3;
            *(ushort8*)&As[srow * LDSS + scol]  = *(const ushort8*)&A[(bm * 128 + srow) * DM + k0 + scol];
            *(ushort8*)&Bcs[srow * LDSS + scol] = *(const ushort8*)&Bct[(bf * 128 + srow) * DM + k0 + scol];
            *(ushort8*)&Bgs[srow * LDSS + scol] = *(const ushort8*)&Bgt[(bf * 128 + srow) * DM + k0 + scol];
        }
        __syncthreads();
        bf16x8 af[4], bcf[4], bgf[4];
        #pragma unroll
        for (int mi = 0; mi < 4; mi++)
            af[mi] = *(const bf16x8*)&As[(wm * 64 + mi * 16 + lr) * LDSS + quad * 8];
        #pragma unroll
        for (int ni = 0; ni < 4; ni++) {
            bcf[ni] = *(const bf16x8*)&Bcs[(wn * 64 + ni * 16 + lr) * LDSS + quad * 8];
            bgf[ni] = *(const bf16x8*)&Bgs[(wn * 64 + ni * 16 + lr) * LDSS + quad * 8];
        }
        #pragma unroll
        for (int mi = 0; mi < 4; mi++)
            #pragma unroll
            for (int ni = 0; ni < 4; ni++) {
                accc[mi][ni] = __builtin_amdgcn_mfma_f32_16x16x32_bf16(af[mi], bcf[ni], accc[mi][ni], 0, 0, 0);
                accg[mi][ni] = __builtin_amdgcn_mfma_f32_16x16x32_bf16(af[mi], bgf[ni], accg[mi][ni], 0, 0, 0);
            }
    }
    // epilogue: C/D layout col=lane&15, row=quad*4+r  [verified m89/m91]
    #pragma unroll
    for (int mi = 0; mi < 4; mi++)
        #pragma unroll
        for (int ni = 0; ni < 4; ni++) {
            int f = bf * 128 + wn * 64 + ni * 16 + lr;
            float bcv = bc[f], bgv = bg[f];
            #pragma unroll
            for (int r = 0; r < 4; r++) {
                int m = bm * 128 + wm * 64 + mi * 16 + quad * 4 + r;
                float cpre = accc[mi][ni][r] + bcv;
                float gpre = accg[mi][ni][r] + bgv;
                float g = sigm(gpre);
                float cla = gelu_f(cpre);
                float tr = bf2f(trop[m * NF + f]);
                fused[m * NF + f] = f2bf(g * tr + (1.0f - g) * cla);
            }
        }
}

// ------------------------------------------------- kernel 6: GEMM2 (fused@Wd + bd)
__global__ __launch_bounds__(256) void gemm2_kernel(
    const unsigned short* __restrict__ A,  // fused [T][1024]
    const unsigned short* __restrict__ Bt, // WdT [256][1024]
    const float* __restrict__ bd, float* __restrict__ out) {
    __shared__ __align__(16) unsigned short As[128 * LDSS];
    __shared__ __align__(16) unsigned short Bs[128 * LDSS];
    const int t = threadIdx.x;
    const int bm = blockIdx.x, bn = blockIdx.y;
    const int wave = t >> 6, lane = t & 63;
    const int wm = wave & 1, wn = wave >> 1;
    const int lr = lane & 15, quad = lane >> 4;

    floatx4 acc[4][4];
    #pragma unroll
    for (int i = 0; i < 4; i++)
        #pragma unroll
        for (int j = 0; j < 4; j++) acc[i][j] = (floatx4)0.0f;

    for (int k0 = 0; k0 < NF; k0 += 32) {
        __syncthreads();
        #pragma unroll
        for (int i = 0; i < 2; i++) {
            int lin = i * 256 + t, srow = lin >> 2, scol = (lin & 3) << 3;
            *(ushort8*)&As[srow * LDSS + scol] = *(const ushort8*)&A[(bm * 128 + srow) * NF + k0 + scol];
            *(ushort8*)&Bs[srow * LDSS + scol] = *(const ushort8*)&Bt[(bn * 128 + srow) * NF + k0 + scol];
        }
        __syncthreads();
        bf16x8 af[4], bf_[4];
        #pragma unroll
        for (int mi = 0; mi < 4; mi++)
            af[mi] = *(const bf16x8*)&As[(wm * 64 + mi * 16 + lr) * LDSS + quad * 8];
        #pragma unroll
        for (int ni = 0; ni < 4; ni++)
            bf_[ni] = *(const bf16x8*)&Bs[(wn * 64 + ni * 16 + lr) * LDSS + quad * 8];
        #pragma unroll
        for (int mi = 0; mi < 4; mi++)
            #pragma unroll
            for (int ni = 0; ni < 4; ni++)
                acc[mi][ni] = __builtin_amdgcn_mfma_f32_16x16x32_bf16(af[mi], bf_[ni], acc[mi][ni], 0, 0, 0);
    }
    #pragma unroll
    for (int mi = 0; mi < 4; mi++)
        #pragma unroll
        for (int ni = 0; ni < 4; ni++) {
            int n = bn * 128 + wn * 64 + ni * 16 + lr;
            float bdv = bd[n];
            #pragma unroll
            for (int r = 0; r < 4; r++) {
                int m = bm * 128 + wm * 64 + mi * 16 + quad * 4 + r;
                out[m * DM + n] = acc[mi][ni][r] + bdv;
            }
        }
}

// ------------------------------------------------------------- launcher
extern "C" void kernel_launch(void* const* d_in, const int* in_sizes, int n_in,
                              void* d_out, int out_size, void* d_ws, size_t ws_size,
                              hipStream_t stream) {
    const float* x     = (const float*)d_in[0];
    const float* Wt    = (const float*)d_in[1];
    const float* bt    = (const float*)d_in[2];
    const float* slx   = (const float*)d_in[3];
    const float* ofx   = (const float*)d_in[4];
    const float* slc   = (const float*)d_in[5];
    const float* ofc   = (const float*)d_in[6];
    const float* alpha = (const float*)d_in[7];
    const float* Wc    = (const float*)d_in[8];
    const float* bc    = (const float*)d_in[9];
    const float* Wg    = (const float*)d_in[10];
    const float* bg    = (const float*)d_in[11];
    const float* Wd    = (const float*)d_in[12];
    const float* bd    = (const float*)d_in[13];
    float* out = (float*)d_out;
    char* ws = (char*)d_ws;

    unsigned int* slot = (unsigned int*)(ws + O_SLOT);
    float* s           = (float*)(ws + O_S);
    unsigned short* Wct = (unsigned short*)(ws + O_WCT);
    unsigned short* Wgt = (unsigned short*)(ws + O_WGT);
    unsigned short* WdT = (unsigned short*)(ws + O_WDT);
    float* WtT          = (float*)(ws + O_WTT);
    unsigned short* xbf = (unsigned short*)(ws + O_XBF);
    int* counts         = (int*)(ws + O_CNT);
    int* cidx           = (int*)(ws + O_CIDX);
    float* cval         = (float*)(ws + O_CVAL);
    unsigned short* trop  = (unsigned short*)(ws + O_TROP);
    unsigned short* fused = (unsigned short*)(ws + O_FUSD);

    pack_kernel<<<1024, 256, 0, stream>>>(Wt, alpha, Wc, Wg, Wd, Wct, Wgt, WdT, WtT, s, slot);
    minmax_kernel<<<128, 256, 0, stream>>>(Wt, slot);
    cand_kernel<<<TTOK, 256, 0, stream>>>(x, slot, xbf, counts, cidx, cval);
    trop_kernel<<<TTOK / 32, 256, 0, stream>>>(x, bt, slx, ofx, slc, ofc, s, WtT,
                                               counts, cidx, cval, trop);
    gemm1_kernel<<<dim3(TTOK / 128, NF / 128), 256, 0, stream>>>(xbf, Wct, Wgt, bc, bg, trop, fused);
    gemm2_kernel<<<dim3(TTOK / 128, DM / 128), 256, 0, stream>>>(fused, WdT, bd, out);
}

// Round 2
// 365.844 us; speedup vs baseline: 1.1343x; 1.1343x over previous
//
#include <hip/hip_runtime.h>

// ---------------------------------------------------------------- constants
#define TTOK 32768
#define DM   256
#define NF   1024
#define KMAX 32

typedef __attribute__((ext_vector_type(8))) unsigned short ushort8;
typedef __attribute__((ext_vector_type(8))) __bf16 bf16x8;
typedef __attribute__((ext_vector_type(4))) float floatx4;

// workspace offsets (all 256B aligned)
constexpr size_t O_SLOT = 0;                                   // 1 uint (max|Wt|)
constexpr size_t O_S    = 256;                                 // 1024 f32 sigmoid(alpha)
constexpr size_t O_WCT  = O_S    + 4096;                       // Wc^T  [1024][256] bf16
constexpr size_t O_WGT  = O_WCT  + (size_t)NF*DM*2;            // Wg^T  [1024][256] bf16
constexpr size_t O_WDT  = O_WGT  + (size_t)NF*DM*2;            // Wd^T  [256][1024] bf16
constexpr size_t O_WTT  = O_WDT  + (size_t)DM*NF*2;            // Wt^T  [256][1024] f32
constexpr size_t O_XBF  = O_WTT  + (size_t)DM*NF*4;            // x bf16 [T][256]
constexpr size_t O_CNT  = O_XBF  + (size_t)TTOK*DM*2;          // counts [T]
constexpr size_t O_CIDX = O_CNT  + (size_t)TTOK*4;             // cand idx [T][KMAX]
constexpr size_t O_CVAL = O_CIDX + (size_t)TTOK*KMAX*4;        // cand val [T][KMAX]
constexpr size_t O_TROP = O_CVAL + (size_t)TTOK*KMAX*4;        // trop bf16 [T][1024]
constexpr size_t O_FUSD = O_TROP + (size_t)TTOK*NF*2;          // fused bf16 [T][1024]

__device__ __forceinline__ float bf2f(unsigned short u) {
    union { unsigned int i; float f; } c; c.i = ((unsigned int)u) << 16; return c.f;
}
__device__ __forceinline__ unsigned short f2bf(float v) {
    union { float f; unsigned int i; } c; c.f = v;
    unsigned int b = c.i;
    return (unsigned short)((b + 0x7FFFu + ((b >> 16) & 1u)) >> 16);
}
__device__ __forceinline__ float sigm(float z) { return 1.0f / (1.0f + __expf(-z)); }
// tanh-gelu: max |diff| vs exact erf-gelu ~3e-3, far under 0.266 tolerance
__device__ __forceinline__ float gelu_f(float x) {
    return x * sigm(1.59576912f * (x + 0.044715f * x * x * x));
}

// ------------------------------------------------- kernel 1: pack weights
__global__ void pack_kernel(const float* __restrict__ Wt, const float* __restrict__ alpha,
                            const float* __restrict__ Wc, const float* __restrict__ Wg,
                            const float* __restrict__ Wd,
                            unsigned short* __restrict__ Wct, unsigned short* __restrict__ Wgt,
                            unsigned short* __restrict__ WdT, float* __restrict__ WtT,
                            float* __restrict__ s, unsigned int* __restrict__ slot) {
    int e = blockIdx.x * 256 + threadIdx.x;
    if (e == 0) *slot = 0u;
    { int f = e >> 8, k = e & 255;           // Wc/Wg are [256][1024]
      Wct[e] = f2bf(Wc[k * NF + f]);
      Wgt[e] = f2bf(Wg[k * NF + f]); }
    { int n = e >> 10, k = e & 1023;         // Wd is [1024][256]
      WdT[e] = f2bf(Wd[k * DM + n]); }
    { int d = e >> 10, f = e & 1023;         // Wt is [1024][256]
      WtT[e] = Wt[f * DM + d]; }
    if (e < NF) s[e] = sigm(alpha[e]);
}

// ------------------------------------------------- kernel 2: max|Wt| reduce
__global__ void minmax_kernel(const float* __restrict__ Wt, unsigned int* __restrict__ slot) {
    int g = blockIdx.x * 256 + threadIdx.x;
    float lm = 0.0f;
    for (int i = g; i < NF * DM; i += 128 * 256) lm = fmaxf(lm, fabsf(Wt[i]));
    #pragma unroll
    for (int o = 32; o > 0; o >>= 1) lm = fmaxf(lm, __shfl_xor(lm, o));
    if ((threadIdx.x & 63) == 0) atomicMax(slot, __float_as_uint(lm)); // |w|>=0: uint order ok
}

// ------------------------------------------------- kernel 3: candidates + x->bf16
__global__ void cand_kernel(const float* __restrict__ x, const unsigned int* __restrict__ slot,
                            unsigned short* __restrict__ xbf, int* __restrict__ counts,
                            int* __restrict__ cidx, float* __restrict__ cval) {
    int i = blockIdx.x, t = threadIdx.x;
    float v = x[i * DM + t];
    xbf[i * DM + t] = f2bf(v);
    float m = v;
    #pragma unroll
    for (int o = 32; o > 0; o >>= 1) m = fmaxf(m, __shfl_xor(m, o));
    __shared__ float wm[4];
    __shared__ int cnt;
    __shared__ int sidx[KMAX];
    __shared__ float sval[KMAX];
    if ((t & 63) == 0) wm[t >> 6] = m;
    if (t == 0) cnt = 0;
    __syncthreads();
    float xmax = fmaxf(fmaxf(wm[0], wm[1]), fmaxf(wm[2], wm[3]));
    float delta = 2.0f * __uint_as_float(*slot);   // >= Wmax - Wmin : exact exclusion bound
    float thr = xmax - delta;
    if (v >= thr) {
        int p = atomicAdd(&cnt, 1);
        if (p < KMAX) { sidx[p] = t; sval[p] = v; }
    }
    __syncthreads();
    int c = cnt;
    if (t == 0) counts[i] = c;
    if (t < (c < KMAX ? c : KMAX)) {
        cidx[i * KMAX + t] = sidx[t];
        cval[i * KMAX + t] = sval[t];
    }
}

// ------------------------------------------------- kernel 4: tropical part
__global__ void trop_kernel(const float* __restrict__ x, const float* __restrict__ bt,
                            const float* __restrict__ slx, const float* __restrict__ ofx,
                            const float* __restrict__ slc, const float* __restrict__ ofc,
                            const float* __restrict__ s, const float* __restrict__ WtT,
                            const int* __restrict__ counts, const int* __restrict__ cidx,
                            const float* __restrict__ cval, unsigned short* __restrict__ trop) {
    __shared__ int sK[32];
    __shared__ int sIdx[32][KMAX];
    __shared__ float sVal[32][KMAX];
    int t = threadIdx.x, tok0 = blockIdx.x * 32;
    if (t < 32) sK[t] = counts[tok0 + t];
    for (int e = t; e < 32 * KMAX; e += 256) {
        int tk = e / KMAX, k = e % KMAX;
        sIdx[tk][k] = cidx[(tok0 + tk) * KMAX + k];
        sVal[tk][k] = cval[(tok0 + tk) * KMAX + k];
    }
    __syncthreads();
    for (int j = 0; j < 4; j++) {
        int f = j * 256 + t;
        float4 a0 = *(const float4*)(slx + f * 8), a1 = *(const float4*)(slx + f * 8 + 4);
        float4 b0 = *(const float4*)(ofx + f * 8), b1 = *(const float4*)(ofx + f * 8 + 4);
        float4 c0 = *(const float4*)(slc + f * 8), c1 = *(const float4*)(slc + f * 8 + 4);
        float4 d0 = *(const float4*)(ofc + f * 8), d1 = *(const float4*)(ofc + f * 8 + 4);
        float btf = bt[f], sf = s[f];
        for (int tk = 0; tk < 32; tk++) {
            int K = sK[tk];
            float tm = -1e30f;
            if (K <= KMAX) {
                for (int k = 0; k < K; k++)
                    tm = fmaxf(tm, sVal[tk][k] + WtT[sIdx[tk][k] * NF + f]);
            } else { // exact fallback (never expected, correctness guard)
                const float* xr = x + (tok0 + tk) * DM;
                for (int d = 0; d < DM; d++) tm = fmaxf(tm, xr[d] + WtT[d * NF + f]);
            }
            float z = tm + btf;
            float cvx = fmaf(z, a0.x, b0.x);
            cvx = fmaxf(cvx, fmaf(z, a0.y, b0.y));
            cvx = fmaxf(cvx, fmaf(z, a0.z, b0.z));
            cvx = fmaxf(cvx, fmaf(z, a0.w, b0.w));
            cvx = fmaxf(cvx, fmaf(z, a1.x, b1.x));
            cvx = fmaxf(cvx, fmaf(z, a1.y, b1.y));
            cvx = fmaxf(cvx, fmaf(z, a1.z, b1.z));
            cvx = fmaxf(cvx, fmaf(z, a1.w, b1.w));
            float ccv = fmaf(z, c0.x, d0.x);
            ccv = fminf(ccv, fmaf(z, c0.y, d0.y));
            ccv = fminf(ccv, fmaf(z, c0.z, d0.z));
            ccv = fminf(ccv, fmaf(z, c0.w, d0.w));
            ccv = fminf(ccv, fmaf(z, c1.x, d1.x));
            ccv = fminf(ccv, fmaf(z, c1.y, d1.y));
            ccv = fminf(ccv, fmaf(z, c1.z, d1.z));
            ccv = fminf(ccv, fmaf(z, c1.w, d1.w));
            float tv = sf * cvx + (1.0f - sf) * ccv;
            trop[(tok0 + tk) * NF + f] = f2bf(tv);
        }
    }
}

// ------------------------------------------------- kernel 5: GEMM1 (x@Wc, x@Wg fused)
// 128(M) x 128(F) tile, BK=32. 512 threads = 8 waves as 2(M)x4(F); each wave 64x32
// dual-output -> acc = 4x2x2 floatx4 = 64 regs (unified VGPR/AGPR), target <=128 total
// so 2 blocks/CU = 4 waves/SIMD (round-1 was 1 wave/SIMD at ~284 regs).
#define LDSS 40  // 32 + 8 pad (ushorts) -> 80B row stride
__global__ __launch_bounds__(512, 4) void gemm1_kernel(
    const unsigned short* __restrict__ A,   // xbf [T][256]
    const unsigned short* __restrict__ Bct, // [1024][256]
    const unsigned short* __restrict__ Bgt, // [1024][256]
    const float* __restrict__ bc, const float* __restrict__ bg,
    const unsigned short* __restrict__ trop, unsigned short* __restrict__ fused) {
    __shared__ __align__(16) unsigned short As[128 * LDSS];
    __shared__ __align__(16) unsigned short Bcs[128 * LDSS];
    __shared__ __align__(16) unsigned short Bgs[128 * LDSS];
    const int t = threadIdx.x;
    const int bm = blockIdx.x, bf = blockIdx.y;
    const int wave = t >> 6, lane = t & 63;
    const int wm = wave & 1, wn = wave >> 1;          // wm in 0..1 (M), wn in 0..3 (F)
    const int lr = lane & 15, quad = lane >> 4;
    const int srow = t >> 2, scol = (t & 3) << 3;     // 512 threads cover 128x32 per buffer

    floatx4 accc[4][2], accg[4][2];
    #pragma unroll
    for (int i = 0; i < 4; i++)
        #pragma unroll
        for (int j = 0; j < 2; j++) { accc[i][j] = (floatx4)0.0f; accg[i][j] = (floatx4)0.0f; }

    for (int k0 = 0; k0 < DM; k0 += 32) {
        __syncthreads();
        *(ushort8*)&As[srow * LDSS + scol]  = *(const ushort8*)&A[(bm * 128 + srow) * DM + k0 + scol];
        *(ushort8*)&Bcs[srow * LDSS + scol] = *(const ushort8*)&Bct[(bf * 128 + srow) * DM + k0 + scol];
        *(ushort8*)&Bgs[srow * LDSS + scol] = *(const ushort8*)&Bgt[(bf * 128 + srow) * DM + k0 + scol];
        __syncthreads();
        bf16x8 af[4], bcf[2], bgf[2];
        #pragma unroll
        for (int mi = 0; mi < 4; mi++)
            af[mi] = *(const bf16x8*)&As[(wm * 64 + mi * 16 + lr) * LDSS + quad * 8];
        #pragma unroll
        for (int ni = 0; ni < 2; ni++) {
            bcf[ni] = *(const bf16x8*)&Bcs[(wn * 32 + ni * 16 + lr) * LDSS + quad * 8];
            bgf[ni] = *(const bf16x8*)&Bgs[(wn * 32 + ni * 16 + lr) * LDSS + quad * 8];
        }
        #pragma unroll
        for (int mi = 0; mi < 4; mi++)
            #pragma unroll
            for (int ni = 0; ni < 2; ni++) {
                accc[mi][ni] = __builtin_amdgcn_mfma_f32_16x16x32_bf16(af[mi], bcf[ni], accc[mi][ni], 0, 0, 0);
                accg[mi][ni] = __builtin_amdgcn_mfma_f32_16x16x32_bf16(af[mi], bgf[ni], accg[mi][ni], 0, 0, 0);
            }
    }
    // epilogue: C/D layout col=lane&15, row=quad*4+r  [verified m89/m91]
    #pragma unroll
    for (int mi = 0; mi < 4; mi++)
        #pragma unroll
        for (int ni = 0; ni < 2; ni++) {
            int f = bf * 128 + wn * 32 + ni * 16 + lr;
            float bcv = bc[f], bgv = bg[f];
            #pragma unroll
            for (int r = 0; r < 4; r++) {
                int m = bm * 128 + wm * 64 + mi * 16 + quad * 4 + r;
                float cpre = accc[mi][ni][r] + bcv;
                float gpre = accg[mi][ni][r] + bgv;
                float g = sigm(gpre);
                float cla = gelu_f(cpre);
                float tr = bf2f(trop[m * NF + f]);
                fused[m * NF + f] = f2bf(g * tr + (1.0f - g) * cla);
            }
        }
}

// ------------------------------------------------- kernel 6: GEMM2 (fused@Wd + bd)
// same 512-thread restructure: 8 waves 2(M)x4(N), wave 64x32, acc 32 regs
__global__ __launch_bounds__(512, 4) void gemm2_kernel(
    const unsigned short* __restrict__ A,  // fused [T][1024]
    const unsigned short* __restrict__ Bt, // WdT [256][1024]
    const float* __restrict__ bd, float* __restrict__ out) {
    __shared__ __align__(16) unsigned short As[128 * LDSS];
    __shared__ __align__(16) unsigned short Bs[128 * LDSS];
    const int t = threadIdx.x;
    const int bm = blockIdx.x, bn = blockIdx.y;
    const int wave = t >> 6, lane = t & 63;
    const int wm = wave & 1, wn = wave >> 1;
    const int lr = lane & 15, quad = lane >> 4;
    const int srow = t >> 2, scol = (t & 3) << 3;

    floatx4 acc[4][2];
    #pragma unroll
    for (int i = 0; i < 4; i++)
        #pragma unroll
        for (int j = 0; j < 2; j++) acc[i][j] = (floatx4)0.0f;

    for (int k0 = 0; k0 < NF; k0 += 32) {
        __syncthreads();
        *(ushort8*)&As[srow * LDSS + scol] = *(const ushort8*)&A[(bm * 128 + srow) * NF + k0 + scol];
        *(ushort8*)&Bs[srow * LDSS + scol] = *(const ushort8*)&Bt[(bn * 128 + srow) * NF + k0 + scol];
        __syncthreads();
        bf16x8 af[4], bf_[2];
        #pragma unroll
        for (int mi = 0; mi < 4; mi++)
            af[mi] = *(const bf16x8*)&As[(wm * 64 + mi * 16 + lr) * LDSS + quad * 8];
        #pragma unroll
        for (int ni = 0; ni < 2; ni++)
            bf_[ni] = *(const bf16x8*)&Bs[(wn * 32 + ni * 16 + lr) * LDSS + quad * 8];
        #pragma unroll
        for (int mi = 0; mi < 4; mi++)
            #pragma unroll
            for (int ni = 0; ni < 2; ni++)
                acc[mi][ni] = __builtin_amdgcn_mfma_f32_16x16x32_bf16(af[mi], bf_[ni], acc[mi][ni], 0, 0, 0);
    }
    #pragma unroll
    for (int mi = 0; mi < 4; mi++)
        #pragma unroll
        for (int ni = 0; ni < 2; ni++) {
            int n = bn * 128 + wn * 32 + ni * 16 + lr;
            float bdv = bd[n];
            #pragma unroll
            for (int r = 0; r < 4; r++) {
                int m = bm * 128 + wm * 64 + mi * 16 + quad * 4 + r;
                out[m * DM + n] = acc[mi][ni][r] + bdv;
            }
        }
}

// ------------------------------------------------------------- launcher
extern "C" void kernel_launch(void* const* d_in, const int* in_sizes, int n_in,
                              void* d_out, int out_size, void* d_ws, size_t ws_size,
                              hipStream_t stream) {
    const float* x     = (const float*)d_in[0];
    const float* Wt    = (const float*)d_in[1];
    const float* bt    = (const float*)d_in[2];
    const float* slx   = (const float*)d_in[3];
    const float* ofx   = (const float*)d_in[4];
    const float* slc   = (const float*)d_in[5];
    const float* ofc   = (const float*)d_in[6];
    const float* alpha = (const float*)d_in[7];
    const float* Wc    = (const float*)d_in[8];
    const float* bc    = (const float*)d_in[9];
    const float* Wg    = (const float*)d_in[10];
    const float* bg    = (const float*)d_in[11];
    const float* Wd    = (const float*)d_in[12];
    const float* bd    = (const float*)d_in[13];
    float* out = (float*)d_out;
    char* ws = (char*)d_ws;

    unsigned int* slot = (unsigned int*)(ws + O_SLOT);
    float* s           = (float*)(ws + O_S);
    unsigned short* Wct = (unsigned short*)(ws + O_WCT);
    unsigned short* Wgt = (unsigned short*)(ws + O_WGT);
    unsigned short* WdT = (unsigned short*)(ws + O_WDT);
    float* WtT          = (float*)(ws + O_WTT);
    unsigned short* xbf = (unsigned short*)(ws + O_XBF);
    int* counts         = (int*)(ws + O_CNT);
    int* cidx           = (int*)(ws + O_CIDX);
    float* cval         = (float*)(ws + O_CVAL);
    unsigned short* trop  = (unsigned short*)(ws + O_TROP);
    unsigned short* fused = (unsigned short*)(ws + O_FUSD);

    pack_kernel<<<1024, 256, 0, stream>>>(Wt, alpha, Wc, Wg, Wd, Wct, Wgt, WdT, WtT, s, slot);
    minmax_kernel<<<128, 256, 0, stream>>>(Wt, slot);
    cand_kernel<<<TTOK, 256, 0, stream>>>(x, slot, xbf, counts, cidx, cval);
    trop_kernel<<<TTOK / 32, 256, 0, stream>>>(x, bt, slx, ofx, slc, ofc, s, WtT,
                                               counts, cidx, cval, trop);
    gemm1_kernel<<<dim3(TTOK / 128, NF / 128), 512, 0, stream>>>(xbf, Wct, Wgt, bc, bg, trop, fused);
    gemm2_kernel<<<dim3(TTOK / 128, DM / 128), 512, 0, stream>>>(fused, WdT, bd, out);
}